// Round 1
// baseline (2409.027 us; speedup 1.0000x reference)
//
#include <hip/hip_runtime.h>
#include <math.h>

#define BB 128
#define NN 2048
#define CIN 3
#define CMID 64
#define HH 128
#define G4 512   // 4*H
#define NCLS 40
#define EPSV 1e-5f

__device__ __forceinline__ float fsigmoid(float x) {
    return 1.0f / (1.0f + __expf(-x));
}
__device__ __forceinline__ float ftanh(float x) {
    // tanh(x) = 2*sigmoid(2x) - 1 ; saturates correctly for |x| large
    return 2.0f / (1.0f + __expf(-2.0f * x)) - 1.0f;
}

__global__ __launch_bounds__(512, 2)
void lstm_seq_kernel(const float* __restrict__ x,
                     const float* __restrict__ conv_w, const float* __restrict__ conv_b,
                     const float* __restrict__ gamma,  const float* __restrict__ beta,
                     const float* __restrict__ rmean,  const float* __restrict__ rvar,
                     const float* __restrict__ W_ih,   const float* __restrict__ W_hh,
                     const float* __restrict__ b_ih,   const float* __restrict__ b_hh,
                     const float* __restrict__ W_out,  const float* __restrict__ b_out,
                     float* __restrict__ out)
{
    __shared__ float x_s[NN * CIN];   // 24 KB: whole input row for this batch elem
    __shared__ float hc_s[CMID];      // conv+BN+ReLU output for current step
    __shared__ float h_s[HH];         // hidden state
    __shared__ float g_s[G4];         // activated gates

    const int b = blockIdx.x;
    const int t = threadIdx.x;

    // ---- stage x[b,:,:] into LDS (coalesced) ----
    const float* xb = x + (size_t)b * NN * CIN;
    for (int i = t; i < NN * CIN; i += 512) x_s[i] = xb[i];

    // ---- fold conv + BN into per-channel affine (threads 0..63, kept in regs) ----
    float ca0 = 0.f, ca1 = 0.f, ca2 = 0.f, cd = 0.f;
    if (t < CMID) {
        float inv = gamma[t] * rsqrtf(rvar[t] + EPSV);
        ca0 = conv_w[t * 3 + 0] * inv;
        ca1 = conv_w[t * 3 + 1] * inv;
        ca2 = conv_w[t * 3 + 2] * inv;
        cd  = (conv_b[t] - rmean[t]) * inv + beta[t];
    }
    if (t < HH) h_s[t] = 0.0f;

    // ---- per-thread gate-row weights in registers ----
    float4 wih[CMID / 4];
    {
        const float4* p = (const float4*)(W_ih + (size_t)t * CMID);
        #pragma unroll
        for (int i = 0; i < CMID / 4; ++i) wih[i] = p[i];
    }
    float4 whh[HH / 4];
    {
        const float4* p = (const float4*)(W_hh + (size_t)t * HH);
        #pragma unroll
        for (int i = 0; i < HH / 4; ++i) whh[i] = p[i];
    }
    const float bias = b_ih[t] + b_hh[t];
    const bool is_tanh_gate = (t >= 2 * HH) && (t < 3 * HH);

    float c_reg = 0.0f;

    __syncthreads();   // x_s, h_s ready

    for (int n = 0; n < NN; ++n) {
        // conv + BN + ReLU for this timestep
        if (t < CMID) {
            float xv0 = x_s[n * 3 + 0];
            float xv1 = x_s[n * 3 + 1];
            float xv2 = x_s[n * 3 + 2];
            float hc = cd + ca0 * xv0 + ca1 * xv1 + ca2 * xv2;
            hc_s[t] = fmaxf(hc, 0.0f);
        }
        __syncthreads();  // hc_s ready

        // g = bias + W_ih[t,:]·hc + W_hh[t,:]·h   (4 accumulators to break dep chain)
        float g0 = bias, g1 = 0.f, g2 = 0.f, g3 = 0.f;
        const float4* hc4 = (const float4*)hc_s;
        #pragma unroll
        for (int c = 0; c < CMID / 4; ++c) {
            float4 v = hc4[c];
            float4 w = wih[c];
            g0 += w.x * v.x; g1 += w.y * v.y; g2 += w.z * v.z; g3 += w.w * v.w;
        }
        const float4* h4 = (const float4*)h_s;
        #pragma unroll
        for (int k = 0; k < HH / 4; ++k) {
            float4 v = h4[k];
            float4 w = whh[k];
            g0 += w.x * v.x; g1 += w.y * v.y; g2 += w.z * v.z; g3 += w.w * v.w;
        }
        float g = (g0 + g1) + (g2 + g3);

        float act = is_tanh_gate ? ftanh(g) : fsigmoid(g);
        g_s[t] = act;
        __syncthreads();  // all gates ready

        if (t < HH) {
            float iv = g_s[t];
            float fv = g_s[HH + t];
            float gv = g_s[2 * HH + t];
            float ov = g_s[3 * HH + t];
            c_reg = fv * c_reg + iv * gv;
            h_s[t] = ov * ftanh(c_reg);
        }
        __syncthreads();  // h_s ready for next step
    }

    // ---- classifier head: out[b,:] = W_out @ h_last + b_out ----
    if (t < NCLS) {
        float acc = b_out[t];
        const float* wrow = W_out + (size_t)t * HH;
        #pragma unroll
        for (int j = 0; j < HH; ++j) acc += wrow[j] * h_s[j];
        out[(size_t)b * NCLS + t] = acc;
    }
}

extern "C" void kernel_launch(void* const* d_in, const int* in_sizes, int n_in,
                              void* d_out, int out_size, void* d_ws, size_t ws_size,
                              hipStream_t stream) {
    const float* x      = (const float*)d_in[0];
    const float* conv_w = (const float*)d_in[1];
    const float* conv_b = (const float*)d_in[2];
    const float* gamma  = (const float*)d_in[3];
    const float* beta   = (const float*)d_in[4];
    const float* rmean  = (const float*)d_in[5];
    const float* rvar   = (const float*)d_in[6];
    const float* W_ih   = (const float*)d_in[7];
    const float* W_hh   = (const float*)d_in[8];
    const float* b_ih   = (const float*)d_in[9];
    const float* b_hh   = (const float*)d_in[10];
    const float* W_out  = (const float*)d_in[11];
    const float* b_out  = (const float*)d_in[12];
    float* out = (float*)d_out;

    lstm_seq_kernel<<<BB, 512, 0, stream>>>(x, conv_w, conv_b, gamma, beta,
                                            rmean, rvar, W_ih, W_hh, b_ih, b_hh,
                                            W_out, b_out, out);
}